// Round 1
// baseline (51.696 us; speedup 1.0000x reference)
//
#include <hip/hip_runtime.h>

#define LSEQ 512
#define NCH  321
#define BATCH 128
#define KAVG 25
#define PAD  12
#define NB1A 64
#define ROWS1A 8   // LSEQ / NB1A

// Exact XTX for t = -512..-1:  [[L, S1],[S1, S2]]
constexpr double S1d  = -131328.0;                 // sum t
constexpr double S2d  = 44870400.0;                // sum t^2
constexpr double DETD = 512.0 * S2d - S1d * S1d;
constexpr double I00  = S2d / DETD;
constexpr double I01  = -S1d / DETD;
constexpr double I11  = 512.0 / DETD;

// Stage 1: partial column sums of W (row-major [p][l]), 8 rows per block.
__global__ __launch_bounds__(512) void colsum_kernel(const float* __restrict__ W,
                                                     float* __restrict__ part0,
                                                     float* __restrict__ part1) {
    int l = threadIdx.x;
    int p0 = blockIdx.x * ROWS1A;
    double s0 = 0.0, s1 = 0.0;
#pragma unroll
    for (int r = 0; r < ROWS1A; ++r) {
        float w = W[(p0 + r) * LSEQ + l];
        s0 += (double)w;
        s1 += (double)(p0 + r - LSEQ) * (double)w;
    }
    part0[blockIdx.x * LSEQ + l] = (float)s0;
    part1[blockIdx.x * LSEQ + l] = (float)s1;
}

// Stage 2: finish column sums, apply moving-average adjoint (replicate pad),
// fold in the exact 2x2 inverse and the bias reductions.
__global__ __launch_bounds__(512) void prep_kernel(const float* __restrict__ part0,
                                                   const float* __restrict__ part1,
                                                   const float* __restrict__ bvec,
                                                   float* __restrict__ alpha,
                                                   float* __restrict__ beta,
                                                   float* __restrict__ consts) {
    __shared__ double w0d[LSEQ], w1d[LSEQ];
    __shared__ double r0[LSEQ], r1[LSEQ];
    int l = threadIdx.x;
    double s0 = 0.0, s1 = 0.0;
    for (int j = 0; j < NB1A; ++j) {
        s0 += (double)part0[j * LSEQ + l];
        s1 += (double)part1[j * LSEQ + l];
    }
    w0d[l] = s0;
    w1d[l] = s1;
    double bv = (double)bvec[l];
    r0[l] = bv;
    r1[l] = (double)(l - LSEQ) * bv;
    __syncthreads();

    // adjoint of AvgPool1d(K=25, replicate-pad 12):
    // g[l'] = (1/K) * ( sum_{m=l'-12..l'+12, in range} w[m]  + boundary extras )
    double g0 = 0.0, g1 = 0.0;
    for (int m = l - PAD; m <= l + PAD; ++m) {
        if (m >= 0 && m < LSEQ) { g0 += w0d[m]; g1 += w1d[m]; }
    }
    if (l == 0) {
        for (int m = 0; m < PAD; ++m) {
            double c = (double)(PAD - m);
            g0 += c * w0d[m]; g1 += c * w1d[m];
        }
    }
    if (l == LSEQ - 1) {
        for (int m = LSEQ - PAD; m < LSEQ; ++m) {
            double c = (double)(m - (LSEQ - PAD - 1));
            g0 += c * w0d[m]; g1 += c * w1d[m];
        }
    }
    g0 *= (1.0 / (double)KAVG);
    g1 *= (1.0 / (double)KAVG);
    alpha[l] = (float)(I00 * g0 + I01 * g1);
    beta[l]  = (float)(I01 * g0 + I11 * g1);

    // reduce bias terms c0 = sum b, c1 = sum (p-512) b[p]
    for (int s = LSEQ / 2; s > 0; s >>= 1) {
        __syncthreads();
        if (l < s) { r0[l] += r0[l + s]; r1[l] += r1[l + s]; }
    }
    if (l == 0) {
        consts[0] = (float)(I00 * r0[0] + I01 * r1[0]);
        consts[1] = (float)(I01 * r0[0] + I11 * r1[0]);
    }
}

// Stage 3: per (b, n-tile of 64): theta0/theta1 via 512-tap correlation
// (4 waves split l-range), then write the affine output over p.
__global__ __launch_bounds__(256) void main_kernel(const float* __restrict__ x,
                                                   const float* __restrict__ alpha,
                                                   const float* __restrict__ beta,
                                                   const float* __restrict__ consts,
                                                   float* __restrict__ out) {
    __shared__ float la[LSEQ], lbb[LSEQ];
    __shared__ float pa[4][64], pb[4][64];
    int tid = threadIdx.x;
    la[tid]        = alpha[tid];
    la[tid + 256]  = alpha[tid + 256];
    lbb[tid]       = beta[tid];
    lbb[tid + 256] = beta[tid + 256];
    float ca = consts[0];
    float cb = consts[1];
    __syncthreads();

    int wave = tid >> 6;
    int lane = tid & 63;
    int n = blockIdx.x * 64 + lane;
    bool valid = (n < NCH);
    int b = blockIdx.y;
    int base = b * (LSEQ * NCH) + n;
    int l0 = wave * 128;

    float a0 = 0.f, a1 = 0.f, a2 = 0.f, a3 = 0.f;
    float b0 = 0.f, b1 = 0.f, b2 = 0.f, b3 = 0.f;
    if (valid) {
        const float* xp = x + base;
#pragma unroll 8
        for (int i = 0; i < 128; i += 4) {
            int l = l0 + i;
            float v0 = xp[(l + 0) * NCH];
            float v1 = xp[(l + 1) * NCH];
            float v2 = xp[(l + 2) * NCH];
            float v3 = xp[(l + 3) * NCH];
            a0 = fmaf(v0, la[l + 0], a0);  b0 = fmaf(v0, lbb[l + 0], b0);
            a1 = fmaf(v1, la[l + 1], a1);  b1 = fmaf(v1, lbb[l + 1], b1);
            a2 = fmaf(v2, la[l + 2], a2);  b2 = fmaf(v2, lbb[l + 2], b2);
            a3 = fmaf(v3, la[l + 3], a3);  b3 = fmaf(v3, lbb[l + 3], b3);
        }
    }
    pa[wave][lane] = (a0 + a1) + (a2 + a3);
    pb[wave][lane] = (b0 + b1) + (b2 + b3);
    __syncthreads();

    float th0 = ((pa[0][lane] + pa[1][lane]) + (pa[2][lane] + pa[3][lane])) + ca;
    float th1 = ((pb[0][lane] + pb[1][lane]) + (pb[2][lane] + pb[3][lane])) + cb;

    if (valid) {
        float* op = out + base;
#pragma unroll 8
        for (int p = l0; p < l0 + 128; ++p) {
            op[p * NCH] = fmaf((float)p, th1, th0);
        }
    }
}

extern "C" void kernel_launch(void* const* d_in, const int* in_sizes, int n_in,
                              void* d_out, int out_size, void* d_ws, size_t ws_size,
                              hipStream_t stream) {
    (void)in_sizes; (void)n_in; (void)out_size; (void)ws_size;
    const float* x    = (const float*)d_in[0];
    const float* W    = (const float*)d_in[1];
    const float* bvec = (const float*)d_in[2];
    float* out = (float*)d_out;

    float* p0     = (float*)d_ws;          // [NB1A * LSEQ]
    float* p1     = p0 + NB1A * LSEQ;      // [NB1A * LSEQ]
    float* alpha  = p1 + NB1A * LSEQ;      // [LSEQ]
    float* beta   = alpha + LSEQ;          // [LSEQ]
    float* consts = beta + LSEQ;           // [2]

    colsum_kernel<<<NB1A, LSEQ, 0, stream>>>(W, p0, p1);
    prep_kernel<<<1, LSEQ, 0, stream>>>(p0, p1, bvec, alpha, beta, consts);
    main_kernel<<<dim3((NCH + 63) / 64, BATCH), 256, 0, stream>>>(x, alpha, beta, consts, out);
}

// Round 2
// 50.526 us; speedup vs baseline: 1.0232x; 1.0232x over previous
//
#include <hip/hip_runtime.h>

#define LSEQ 512
#define NCH  321
#define BATCH 128
#define KAVG 25
#define PAD  12
#define NB1A 32
#define ROWS1A 16   // LSEQ / NB1A

// Exact XTX for t = -512..-1:  [[L, S1],[S1, S2]]
constexpr double S1d  = -131328.0;                 // sum t
constexpr double S2d  = 44870400.0;                // sum t^2
constexpr double DETD = 512.0 * S2d - S1d * S1d;
constexpr double I00  = S2d / DETD;
constexpr double I01  = -S1d / DETD;
constexpr double I11  = 512.0 / DETD;

// Stage 1: partial column sums of W (row-major [p][l]), 16 rows per block.
__global__ __launch_bounds__(512) void colsum_kernel(const float* __restrict__ W,
                                                     float* __restrict__ part0,
                                                     float* __restrict__ part1) {
    int l = threadIdx.x;
    int p0 = blockIdx.x * ROWS1A;
    double s0 = 0.0, s1 = 0.0;
#pragma unroll
    for (int r = 0; r < ROWS1A; ++r) {
        float w = W[(p0 + r) * LSEQ + l];
        s0 += (double)w;
        s1 += (double)(p0 + r - LSEQ) * (double)w;
    }
    part0[blockIdx.x * LSEQ + l] = (float)s0;
    part1[blockIdx.x * LSEQ + l] = (float)s1;
}

// Stage 2: finish column sums, apply moving-average adjoint (replicate pad),
// fold in the exact 2x2 inverse and the bias reductions.
__global__ __launch_bounds__(512) void prep_kernel(const float* __restrict__ part0,
                                                   const float* __restrict__ part1,
                                                   const float* __restrict__ bvec,
                                                   float* __restrict__ alpha,
                                                   float* __restrict__ beta,
                                                   float* __restrict__ consts) {
    __shared__ double w0d[LSEQ], w1d[LSEQ];
    __shared__ double r0[LSEQ], r1[LSEQ];
    int l = threadIdx.x;
    double s0 = 0.0, s1 = 0.0;
    for (int j = 0; j < NB1A; ++j) {
        s0 += (double)part0[j * LSEQ + l];
        s1 += (double)part1[j * LSEQ + l];
    }
    w0d[l] = s0;
    w1d[l] = s1;
    double bv = (double)bvec[l];
    r0[l] = bv;
    r1[l] = (double)(l - LSEQ) * bv;
    __syncthreads();

    // adjoint of AvgPool1d(K=25, replicate-pad 12):
    double g0 = 0.0, g1 = 0.0;
    for (int m = l - PAD; m <= l + PAD; ++m) {
        if (m >= 0 && m < LSEQ) { g0 += w0d[m]; g1 += w1d[m]; }
    }
    if (l == 0) {
        for (int m = 0; m < PAD; ++m) {
            double c = (double)(PAD - m);
            g0 += c * w0d[m]; g1 += c * w1d[m];
        }
    }
    if (l == LSEQ - 1) {
        for (int m = LSEQ - PAD; m < LSEQ; ++m) {
            double c = (double)(m - (LSEQ - PAD - 1));
            g0 += c * w0d[m]; g1 += c * w1d[m];
        }
    }
    g0 *= (1.0 / (double)KAVG);
    g1 *= (1.0 / (double)KAVG);
    alpha[l] = (float)(I00 * g0 + I01 * g1);
    beta[l]  = (float)(I01 * g0 + I11 * g1);

    for (int s = LSEQ / 2; s > 0; s >>= 1) {
        __syncthreads();
        if (l < s) { r0[l] += r0[l + s]; r1[l] += r1[l + s]; }
    }
    if (l == 0) {
        consts[0] = (float)(I00 * r0[0] + I01 * r1[0]);
        consts[1] = (float)(I01 * r0[0] + I11 * r1[0]);
    }
}

// Stage 3 (reduce): theta0/theta1 per (b, n). 8 waves split the l-range.
__global__ __launch_bounds__(512) void reduce_kernel(const float* __restrict__ x,
                                                     const float* __restrict__ alpha,
                                                     const float* __restrict__ beta,
                                                     const float* __restrict__ consts,
                                                     float* __restrict__ T0,
                                                     float* __restrict__ T1) {
    __shared__ float la[LSEQ], lbb[LSEQ];
    __shared__ float pa[8][64], pb[8][64];
    int tid = threadIdx.x;
    la[tid]  = alpha[tid];
    lbb[tid] = beta[tid];
    __syncthreads();

    int wave = tid >> 6;
    int lane = tid & 63;
    int n = blockIdx.x * 64 + lane;
    bool valid = (n < NCH);
    int b = blockIdx.y;
    int l0 = wave * 64;

    float a0 = 0.f, a1 = 0.f, a2 = 0.f, a3 = 0.f;
    float b0 = 0.f, b1 = 0.f, b2 = 0.f, b3 = 0.f;
    if (valid) {
        const float* xp = x + (size_t)b * (LSEQ * NCH) + n;
#pragma unroll
        for (int i = 0; i < 64; i += 4) {
            int l = l0 + i;
            float v0 = xp[(l + 0) * NCH];
            float v1 = xp[(l + 1) * NCH];
            float v2 = xp[(l + 2) * NCH];
            float v3 = xp[(l + 3) * NCH];
            a0 = fmaf(v0, la[l + 0], a0);  b0 = fmaf(v0, lbb[l + 0], b0);
            a1 = fmaf(v1, la[l + 1], a1);  b1 = fmaf(v1, lbb[l + 1], b1);
            a2 = fmaf(v2, la[l + 2], a2);  b2 = fmaf(v2, lbb[l + 2], b2);
            a3 = fmaf(v3, la[l + 3], a3);  b3 = fmaf(v3, lbb[l + 3], b3);
        }
    }
    pa[wave][lane] = (a0 + a1) + (a2 + a3);
    pb[wave][lane] = (b0 + b1) + (b2 + b3);
    __syncthreads();

    if (tid < 64 && valid) {
        float s0 = 0.f, s1 = 0.f;
#pragma unroll
        for (int w = 0; w < 8; ++w) { s0 += pa[w][tid]; s1 += pb[w][tid]; }
        T0[b * NCH + n] = s0 + consts[0];
        T1[b * NCH + n] = s1 + consts[1];
    }
}

// Stage 4 (write): out[b,p,n] = T0[b,n] + p*T1[b,n].
// Each block writes 8 full rows (2568 floats, contiguous) of one batch.
#define ROWS_W 8
#define CHUNK (ROWS_W * NCH)   // 2568 floats, divisible by 4
__global__ __launch_bounds__(256) void write_kernel(const float* __restrict__ T0,
                                                    const float* __restrict__ T1,
                                                    float* __restrict__ out) {
    __shared__ float t0s[NCH], t1s[NCH];
    int tid = threadIdx.x;
    int b = blockIdx.y;
    for (int i = tid; i < NCH; i += 256) {
        t0s[i] = T0[b * NCH + i];
        t1s[i] = T1[b * NCH + i];
    }
    __syncthreads();

    int pbase = blockIdx.x * ROWS_W;
    float* op = out + (size_t)b * (LSEQ * NCH) + (size_t)pbase * NCH;
#pragma unroll
    for (int k = 0; k < 3; ++k) {
        int g = tid + k * 256;           // float4 group index
        if (g < CHUNK / 4) {
            int c0 = 4 * g;
            int ploc = c0 / NCH;
            int n = c0 - ploc * NCH;
            float pf = (float)(pbase + ploc);
            float4 v;
            v.x = fmaf(pf, t1s[n], t0s[n]); if (++n == NCH) { n = 0; pf += 1.f; }
            v.y = fmaf(pf, t1s[n], t0s[n]); if (++n == NCH) { n = 0; pf += 1.f; }
            v.z = fmaf(pf, t1s[n], t0s[n]); if (++n == NCH) { n = 0; pf += 1.f; }
            v.w = fmaf(pf, t1s[n], t0s[n]);
            *reinterpret_cast<float4*>(op + c0) = v;
        }
    }
}

extern "C" void kernel_launch(void* const* d_in, const int* in_sizes, int n_in,
                              void* d_out, int out_size, void* d_ws, size_t ws_size,
                              hipStream_t stream) {
    (void)in_sizes; (void)n_in; (void)out_size; (void)ws_size;
    const float* x    = (const float*)d_in[0];
    const float* W    = (const float*)d_in[1];
    const float* bvec = (const float*)d_in[2];
    float* out = (float*)d_out;

    // ws layout: [alpha 512][beta 512][consts 2][region: p0/p1 then T0/T1]
    float* alpha  = (float*)d_ws;
    float* beta   = alpha + LSEQ;
    float* consts = beta + LSEQ;
    float* region = consts + 2;
    float* p0 = region;                    // [NB1A*LSEQ] (colsum/prep only)
    float* p1 = p0 + NB1A * LSEQ;
    float* T0 = region;                    // [BATCH*NCH] (reduce/write, reuses p0/p1)
    float* T1 = T0 + BATCH * NCH;

    colsum_kernel<<<NB1A, LSEQ, 0, stream>>>(W, p0, p1);
    prep_kernel<<<1, LSEQ, 0, stream>>>(p0, p1, bvec, alpha, beta, consts);
    reduce_kernel<<<dim3((NCH + 63) / 64, BATCH), 512, 0, stream>>>(x, alpha, beta, consts, T0, T1);
    write_kernel<<<dim3(LSEQ / ROWS_W, BATCH), 256, 0, stream>>>(T0, T1, out);
}

// Round 3
// 49.567 us; speedup vs baseline: 1.0430x; 1.0194x over previous
//
#include <hip/hip_runtime.h>

#define LSEQ 512
#define NCH  321
#define BATCH 128
#define KAVG 25
#define PAD  12
#define NB1A 8
#define ROWS1A 64   // LSEQ / NB1A

// Exact XTX for t = -512..-1:  [[L, S1],[S1, S2]]
constexpr double S1d  = -131328.0;                 // sum t
constexpr double S2d  = 44870400.0;                // sum t^2
constexpr double DETD = 512.0 * S2d - S1d * S1d;
constexpr double I00  = S2d / DETD;
constexpr double I01  = -S1d / DETD;
constexpr double I11  = 512.0 / DETD;

// Stage 1: partial column sums of W (row-major [p][l]), 64 rows per block.
// 8 blocks only, but each thread has 64 independent unrolled loads in flight.
__global__ __launch_bounds__(512) void colsum_kernel(const float* __restrict__ W,
                                                     float* __restrict__ part0,
                                                     float* __restrict__ part1) {
    int l = threadIdx.x;
    int p0 = blockIdx.x * ROWS1A;
    double s0 = 0.0, s1 = 0.0;
#pragma unroll
    for (int r = 0; r < ROWS1A; ++r) {
        float w = W[(p0 + r) * LSEQ + l];
        s0 += (double)w;
        s1 += (double)(p0 + r - LSEQ) * (double)w;
    }
    part0[blockIdx.x * LSEQ + l] = (float)s0;
    part1[blockIdx.x * LSEQ + l] = (float)s1;
}

// Stage 2: finish column sums (8-way fan-in, fully unrolled), apply
// moving-average adjoint (replicate pad), fold in exact inverse + bias.
__global__ __launch_bounds__(512) void prep_kernel(const float* __restrict__ part0,
                                                   const float* __restrict__ part1,
                                                   const float* __restrict__ bvec,
                                                   float* __restrict__ alpha,
                                                   float* __restrict__ beta,
                                                   float* __restrict__ consts) {
    __shared__ double w0d[LSEQ], w1d[LSEQ];
    __shared__ double r0[LSEQ], r1[LSEQ];
    int l = threadIdx.x;
    double s0 = 0.0, s1 = 0.0;
#pragma unroll
    for (int j = 0; j < NB1A; ++j) {
        s0 += (double)part0[j * LSEQ + l];
        s1 += (double)part1[j * LSEQ + l];
    }
    w0d[l] = s0;
    w1d[l] = s1;
    double bv = (double)bvec[l];
    r0[l] = bv;
    r1[l] = (double)(l - LSEQ) * bv;
    __syncthreads();

    // adjoint of AvgPool1d(K=25, replicate-pad 12):
    double g0 = 0.0, g1 = 0.0;
    for (int m = l - PAD; m <= l + PAD; ++m) {
        if (m >= 0 && m < LSEQ) { g0 += w0d[m]; g1 += w1d[m]; }
    }
    if (l == 0) {
        for (int m = 0; m < PAD; ++m) {
            double c = (double)(PAD - m);
            g0 += c * w0d[m]; g1 += c * w1d[m];
        }
    }
    if (l == LSEQ - 1) {
        for (int m = LSEQ - PAD; m < LSEQ; ++m) {
            double c = (double)(m - (LSEQ - PAD - 1));
            g0 += c * w0d[m]; g1 += c * w1d[m];
        }
    }
    g0 *= (1.0 / (double)KAVG);
    g1 *= (1.0 / (double)KAVG);
    alpha[l] = (float)(I00 * g0 + I01 * g1);
    beta[l]  = (float)(I01 * g0 + I11 * g1);

    for (int s = LSEQ / 2; s > 0; s >>= 1) {
        __syncthreads();
        if (l < s) { r0[l] += r0[l + s]; r1[l] += r1[l + s]; }
    }
    if (l == 0) {
        consts[0] = (float)(I00 * r0[0] + I01 * r1[0]);
        consts[1] = (float)(I01 * r0[0] + I11 * r1[0]);
    }
}

// Stage 3 (reduce): theta0/theta1 per (b, n). 8 waves split the l-range.
__global__ __launch_bounds__(512) void reduce_kernel(const float* __restrict__ x,
                                                     const float* __restrict__ alpha,
                                                     const float* __restrict__ beta,
                                                     const float* __restrict__ consts,
                                                     float* __restrict__ T0,
                                                     float* __restrict__ T1) {
    __shared__ float la[LSEQ], lbb[LSEQ];
    __shared__ float pa[8][64], pb[8][64];
    int tid = threadIdx.x;
    la[tid]  = alpha[tid];
    lbb[tid] = beta[tid];
    __syncthreads();

    int wave = tid >> 6;
    int lane = tid & 63;
    int n = blockIdx.x * 64 + lane;
    bool valid = (n < NCH);
    int b = blockIdx.y;
    int l0 = wave * 64;

    float a0 = 0.f, a1 = 0.f, a2 = 0.f, a3 = 0.f;
    float b0 = 0.f, b1 = 0.f, b2 = 0.f, b3 = 0.f;
    if (valid) {
        const float* xp = x + (size_t)b * (LSEQ * NCH) + n;
#pragma unroll
        for (int i = 0; i < 64; i += 4) {
            int l = l0 + i;
            float v0 = xp[(l + 0) * NCH];
            float v1 = xp[(l + 1) * NCH];
            float v2 = xp[(l + 2) * NCH];
            float v3 = xp[(l + 3) * NCH];
            a0 = fmaf(v0, la[l + 0], a0);  b0 = fmaf(v0, lbb[l + 0], b0);
            a1 = fmaf(v1, la[l + 1], a1);  b1 = fmaf(v1, lbb[l + 1], b1);
            a2 = fmaf(v2, la[l + 2], a2);  b2 = fmaf(v2, lbb[l + 2], b2);
            a3 = fmaf(v3, la[l + 3], a3);  b3 = fmaf(v3, lbb[l + 3], b3);
        }
    }
    pa[wave][lane] = (a0 + a1) + (a2 + a3);
    pb[wave][lane] = (b0 + b1) + (b2 + b3);
    __syncthreads();

    if (tid < 64 && valid) {
        float s0 = 0.f, s1 = 0.f;
#pragma unroll
        for (int w = 0; w < 8; ++w) { s0 += pa[w][tid]; s1 += pb[w][tid]; }
        T0[b * NCH + n] = s0 + consts[0];
        T1[b * NCH + n] = s1 + consts[1];
    }
}

// Stage 4 (write): out[b,p,n] = T0[b,n] + p*T1[b,n].
// Each block writes 8 full rows (2568 floats, contiguous) of one batch.
#define ROWS_W 8
#define CHUNK (ROWS_W * NCH)   // 2568 floats, divisible by 4
__global__ __launch_bounds__(256) void write_kernel(const float* __restrict__ T0,
                                                    const float* __restrict__ T1,
                                                    float* __restrict__ out) {
    __shared__ float t0s[NCH], t1s[NCH];
    int tid = threadIdx.x;
    int b = blockIdx.y;
    for (int i = tid; i < NCH; i += 256) {
        t0s[i] = T0[b * NCH + i];
        t1s[i] = T1[b * NCH + i];
    }
    __syncthreads();

    int pbase = blockIdx.x * ROWS_W;
    float* op = out + (size_t)b * (LSEQ * NCH) + (size_t)pbase * NCH;
#pragma unroll
    for (int k = 0; k < 3; ++k) {
        int g = tid + k * 256;           // float4 group index
        if (g < CHUNK / 4) {
            int c0 = 4 * g;
            int ploc = c0 / NCH;
            int n = c0 - ploc * NCH;
            float pf = (float)(pbase + ploc);
            float4 v;
            v.x = fmaf(pf, t1s[n], t0s[n]); if (++n == NCH) { n = 0; pf += 1.f; }
            v.y = fmaf(pf, t1s[n], t0s[n]); if (++n == NCH) { n = 0; pf += 1.f; }
            v.z = fmaf(pf, t1s[n], t0s[n]); if (++n == NCH) { n = 0; pf += 1.f; }
            v.w = fmaf(pf, t1s[n], t0s[n]);
            *reinterpret_cast<float4*>(op + c0) = v;
        }
    }
}

extern "C" void kernel_launch(void* const* d_in, const int* in_sizes, int n_in,
                              void* d_out, int out_size, void* d_ws, size_t ws_size,
                              hipStream_t stream) {
    (void)in_sizes; (void)n_in; (void)out_size; (void)ws_size;
    const float* x    = (const float*)d_in[0];
    const float* W    = (const float*)d_in[1];
    const float* bvec = (const float*)d_in[2];
    float* out = (float*)d_out;

    // ws layout: [alpha 512][beta 512][consts 2][region: p0/p1 then T0/T1]
    float* alpha  = (float*)d_ws;
    float* beta   = alpha + LSEQ;
    float* consts = beta + LSEQ;
    float* region = consts + 2;
    float* p0 = region;                    // [NB1A*LSEQ] (colsum/prep only)
    float* p1 = p0 + NB1A * LSEQ;
    float* T0 = region;                    // [BATCH*NCH] (reduce/write, reuses p0/p1)
    float* T1 = T0 + BATCH * NCH;

    colsum_kernel<<<NB1A, LSEQ, 0, stream>>>(W, p0, p1);
    prep_kernel<<<1, LSEQ, 0, stream>>>(p0, p1, bvec, alpha, beta, consts);
    reduce_kernel<<<dim3((NCH + 63) / 64, BATCH), 512, 0, stream>>>(x, alpha, beta, consts, T0, T1);
    write_kernel<<<dim3(LSEQ / ROWS_W, BATCH), 256, 0, stream>>>(T0, T1, out);
}

// Round 4
// 41.741 us; speedup vs baseline: 1.2385x; 1.1875x over previous
//
#include <hip/hip_runtime.h>

#define LSEQ 512
#define NCH  321
#define BATCH 128
#define KAVG 25
#define PAD  12
#define NB1A 8
#define ROWS1A 64      // LSEQ / NB1A

#define BANDS 4
#define BROWS 128      // rows per band (LSEQ / BANDS)
#define ITERS 64       // BROWS / 2 (two rows per iteration)
#define RTHREADS 704   // 11 waves; 2*NCH = 642 active lanes

#define ROWS_W 32
#define WBLOCKS (LSEQ / ROWS_W)   // 16
#define CHUNKW  (ROWS_W * NCH)    // 10272 dwords, /4 = 2568 float4

// Exact XTX for t = -512..-1:  [[L, S1],[S1, S2]]
constexpr double S1d  = -131328.0;
constexpr double S2d  = 44870400.0;
constexpr double DETD = 512.0 * S2d - S1d * S1d;
constexpr double I00  = S2d / DETD;
constexpr double I01  = -S1d / DETD;
constexpr double I11  = 512.0 / DETD;

// Stage 1: partial column sums of W (row-major [p][l]), 64 rows per block.
__global__ __launch_bounds__(512) void colsum_kernel(const float* __restrict__ W,
                                                     float* __restrict__ part0,
                                                     float* __restrict__ part1) {
    int l = threadIdx.x;
    int p0 = blockIdx.x * ROWS1A;
    double s0 = 0.0, s1 = 0.0;
#pragma unroll
    for (int r = 0; r < ROWS1A; ++r) {
        float w = W[(p0 + r) * LSEQ + l];
        s0 += (double)w;
        s1 += (double)(p0 + r - LSEQ) * (double)w;
    }
    part0[blockIdx.x * LSEQ + l] = (float)s0;
    part1[blockIdx.x * LSEQ + l] = (float)s1;
}

// Stage 2 (reduce, streaming): block = (band, b). Inline prep prologue builds
// alpha/beta (+ bias consts) in LDS, then the block streams 128 contiguous
// rows of x (two rows per iteration across 642 lanes), each thread owning a
// fixed channel n. Band partials go to P0/P1; consts folded into band 0.
__global__ __launch_bounds__(RTHREADS) void reduce_kernel(const float* __restrict__ x,
                                                          const float* __restrict__ part0,
                                                          const float* __restrict__ part1,
                                                          const float* __restrict__ bvec,
                                                          float* __restrict__ P0,
                                                          float* __restrict__ P1) {
    __shared__ double w0d[LSEQ], w1d[LSEQ];
    __shared__ double r0[LSEQ], r1[LSEQ];
    __shared__ float la[LSEQ], lbb[LSEQ];
    __shared__ float cbuf0[NCH], cbuf1[NCH];
    __shared__ float cc0, cc1;

    int tid = threadIdx.x;

    // ---- inline prep (threads 0..511) ----
    if (tid < LSEQ) {
        int l = tid;
        double s0 = 0.0, s1 = 0.0;
#pragma unroll
        for (int j = 0; j < NB1A; ++j) {
            s0 += (double)part0[j * LSEQ + l];
            s1 += (double)part1[j * LSEQ + l];
        }
        w0d[l] = s0;
        w1d[l] = s1;
        double bv = (double)bvec[l];
        r0[l] = bv;
        r1[l] = (double)(l - LSEQ) * bv;
    }
    __syncthreads();
    if (tid < LSEQ) {
        int l = tid;
        double g0 = 0.0, g1 = 0.0;
        for (int m = l - PAD; m <= l + PAD; ++m) {
            if (m >= 0 && m < LSEQ) { g0 += w0d[m]; g1 += w1d[m]; }
        }
        if (l == 0) {
            for (int m = 0; m < PAD; ++m) {
                double c = (double)(PAD - m);
                g0 += c * w0d[m]; g1 += c * w1d[m];
            }
        }
        if (l == LSEQ - 1) {
            for (int m = LSEQ - PAD; m < LSEQ; ++m) {
                double c = (double)(m - (LSEQ - PAD - 1));
                g0 += c * w0d[m]; g1 += c * w1d[m];
            }
        }
        g0 *= (1.0 / (double)KAVG);
        g1 *= (1.0 / (double)KAVG);
        la[l]  = (float)(I00 * g0 + I01 * g1);
        lbb[l] = (float)(I01 * g0 + I11 * g1);
    }
    for (int s = LSEQ / 2; s > 0; s >>= 1) {
        __syncthreads();
        if (tid < s) { r0[tid] += r0[tid + s]; r1[tid] += r1[tid + s]; }
    }
    if (tid == 0) {
        cc0 = (float)(I00 * r0[0] + I01 * r1[0]);
        cc1 = (float)(I01 * r0[0] + I11 * r1[0]);
    }
    __syncthreads();

    // ---- streaming accumulation: two full rows per iteration ----
    int band = blockIdx.x;
    int b    = blockIdx.y;
    int half = (tid >= NCH) ? 1 : 0;
    int n    = tid - half * NCH;
    bool act = (tid < 2 * NCH);
    int l0   = band * BROWS;

    float a = 0.f, bb = 0.f;
    if (act) {
        const float* xp = x + (size_t)b * (LSEQ * NCH) + (size_t)l0 * NCH + tid;
#pragma unroll 8
        for (int it = 0; it < ITERS; ++it) {
            float v = xp[it * (2 * NCH)];
            int l = l0 + 2 * it + half;
            a  = fmaf(v, la[l],  a);
            bb = fmaf(v, lbb[l], bb);
        }
    }

    // combine the two half-row owners of each n (deterministic two-step)
    if (act && half == 0) { cbuf0[n] = a; cbuf1[n] = bb; }
    __syncthreads();
    if (act && half == 1) { cbuf0[n] += a; cbuf1[n] += bb; }
    __syncthreads();

    if (tid < NCH) {
        float add0 = (band == 0) ? cc0 : 0.f;
        float add1 = (band == 0) ? cc1 : 0.f;
        P0[(band * BATCH + b) * NCH + tid] = cbuf0[tid] + add0;
        P1[(band * BATCH + b) * NCH + tid] = cbuf1[tid] + add1;
    }
}

// Stage 3 (write): out[b,p,n] = T0[b,n] + p*T1[b,n], T = sum of band partials.
// Each block writes 32 full rows (41 KB contiguous) of one batch, float4.
__global__ __launch_bounds__(256) void write_kernel(const float* __restrict__ P0,
                                                    const float* __restrict__ P1,
                                                    float* __restrict__ out) {
    __shared__ float t0s[NCH], t1s[NCH];
    int tid = threadIdx.x;
    int b = blockIdx.y;
    for (int i = tid; i < NCH; i += 256) {
        float s0 = 0.f, s1 = 0.f;
#pragma unroll
        for (int band = 0; band < BANDS; ++band) {
            s0 += P0[(band * BATCH + b) * NCH + i];
            s1 += P1[(band * BATCH + b) * NCH + i];
        }
        t0s[i] = s0;
        t1s[i] = s1;
    }
    __syncthreads();

    int pbase = blockIdx.x * ROWS_W;
    float* op = out + (size_t)b * (LSEQ * NCH) + (size_t)pbase * NCH;
    for (int g = tid; g < CHUNKW / 4; g += 256) {
        int c0 = 4 * g;
        int ploc = c0 / NCH;
        int n = c0 - ploc * NCH;
        float pf = (float)(pbase + ploc);
        float4 v;
        v.x = fmaf(pf, t1s[n], t0s[n]); if (++n == NCH) { n = 0; pf += 1.f; }
        v.y = fmaf(pf, t1s[n], t0s[n]); if (++n == NCH) { n = 0; pf += 1.f; }
        v.z = fmaf(pf, t1s[n], t0s[n]); if (++n == NCH) { n = 0; pf += 1.f; }
        v.w = fmaf(pf, t1s[n], t0s[n]);
        *reinterpret_cast<float4*>(op + c0) = v;
    }
}

extern "C" void kernel_launch(void* const* d_in, const int* in_sizes, int n_in,
                              void* d_out, int out_size, void* d_ws, size_t ws_size,
                              hipStream_t stream) {
    (void)in_sizes; (void)n_in; (void)out_size; (void)ws_size;
    const float* x    = (const float*)d_in[0];
    const float* W    = (const float*)d_in[1];
    const float* bvec = (const float*)d_in[2];
    float* out = (float*)d_out;

    // ws layout: [part0 8*512][part1 8*512][P0 4*128*321][P1 4*128*321]
    float* p0 = (float*)d_ws;
    float* p1 = p0 + NB1A * LSEQ;
    float* P0 = p1 + NB1A * LSEQ;
    float* P1 = P0 + BANDS * BATCH * NCH;

    colsum_kernel<<<NB1A, LSEQ, 0, stream>>>(W, p0, p1);
    reduce_kernel<<<dim3(BANDS, BATCH), RTHREADS, 0, stream>>>(x, p0, p1, bvec, P0, P1);
    write_kernel<<<dim3(WBLOCKS, BATCH), 256, 0, stream>>>(P0, P1, out);
}